// Round 9
// baseline (599.415 us; speedup 1.0000x reference)
//
#include <hip/hip_runtime.h>
#include <hip/hip_fp16.h>
#include <hip/hip_cooperative_groups.h>
#include <math.h>

namespace cg = cooperative_groups;

// GAT 2-layer forward, MI355X.
// memset(gcur) -> k_front[bin || mfma-gemm1+att1] -> k_scatter(CSR build)
//   -> k_back (cooperative: agg1 -> gridsync -> gemm2+att2 -> gridsync -> agg2)

constexpr int CAP  = 64;    // max in-degree (Poisson(16)+1, P(>=63)~4e-19)
constexpr int MAXB = 512;   // bin counter slots; gcur[MAXB] = global edge cursor
constexpr int TILE = 2048;  // edges per bin block
constexpr int BCAP = 5120;  // records per 256-node bin (mean 4352, ~11 sigma)
constexpr int HTS  = 72;    // htile row stride (f16) -> bank-conflict-free epilogue

typedef _Float16 f16x8 __attribute__((ext_vector_type(8)));
typedef float    f32x4 __attribute__((ext_vector_type(4)));

// ---- fused front: edge binning blocks + MFMA gemm1 blocks (att1 in epilogue) ----
__global__ __launch_bounds__(256)
void k_front(const int* __restrict__ src, const int* __restrict__ dst,
             int* __restrict__ gcur, unsigned* __restrict__ binbuf, int E, int Gbin,
             const float* __restrict__ x, const float* __restrict__ W,
             const float* __restrict__ al1, const float* __restrict__ ar1,
             __half* __restrict__ h1, float* __restrict__ el, float* __restrict__ er,
             int nnodes)
{
    __shared__ alignas(16) char smem[32 * 1024];
    const int tid = threadIdx.x;

    if ((int)blockIdx.x < Gbin) {
        // ---- bin role: 2048 edges -> packed records (src<<8 | dst&255) ----
        int* cnt  = (int*)smem;
        int* base = cnt + MAXB;
        for (int b = tid; b < MAXB; b += 256) cnt[b] = 0;
        __syncthreads();
        const int e0 = blockIdx.x * TILE;
        int lo[8]; unsigned rec[8]; int bn[8];
        #pragma unroll
        for (int u = 0; u < 8; u++) {
            const int e = e0 + u * 256 + tid;
            if (e < E) {
                const int d = dst[e];
                bn[u]  = d >> 8;
                rec[u] = ((unsigned)src[e] << 8) | (unsigned)(d & 255);
                lo[u]  = atomicAdd(&cnt[bn[u]], 1);
            } else bn[u] = -1;
        }
        __syncthreads();
        for (int b = tid; b < MAXB; b += 256) {
            const int c = cnt[b];
            base[b] = c ? atomicAdd(&gcur[b], c) : 0;
        }
        __syncthreads();
        #pragma unroll
        for (int u = 0; u < 8; u++) if (bn[u] >= 0) {
            const int p = base[bn[u]] + lo[u];
            if ((unsigned)p < (unsigned)BCAP)
                binbuf[(long)bn[u] * BCAP + p] = rec[u];
        }
        return;
    }

    // ---- gemm role: 64 nodes, x(fp32->fp16 swizzled LDS) @ W1 via MFMA 16x16x32 ----
    _Float16* xs = (_Float16*)smem;            // 64 x 128, XOR-swizzled (16KB)
    _Float16* Wh = xs + 64 * 128;              // 128 x 64 (16KB)
    const int node0 = ((int)blockIdx.x - Gbin) * 64;

    for (int c = tid; c < 1024; c += 256) {
        const int row = c >> 4, k8 = c & 15;
        const int n = node0 + row;
        float4 v0 = make_float4(0, 0, 0, 0), v1 = v0;
        if (n < nnodes) {
            v0 = ((const float4*)x)[(long)n * 32 + k8 * 2];
            v1 = ((const float4*)x)[(long)n * 32 + k8 * 2 + 1];
        }
        f16x8 h;
        h[0] = v0.x; h[1] = v0.y; h[2] = v0.z; h[3] = v0.w;
        h[4] = v1.x; h[5] = v1.y; h[6] = v1.z; h[7] = v1.w;
        const int off = (row * 256 + k8 * 16) ^ ((row & 7) << 4);
        *(f16x8*)((char*)xs + off) = h;
    }
    for (int c = tid; c < 1024; c += 256) {
        const int k = c >> 3, j8 = (c & 7) * 8;
        float4 v0 = ((const float4*)W)[(k * 64 + j8) >> 2];
        float4 v1 = ((const float4*)W)[((k * 64 + j8) >> 2) + 1];
        f16x8 h;
        h[0] = v0.x; h[1] = v0.y; h[2] = v0.z; h[3] = v0.w;
        h[4] = v1.x; h[5] = v1.y; h[6] = v1.z; h[7] = v1.w;
        *(f16x8*)(Wh + k * 64 + j8) = h;
    }
    __syncthreads();

    const int wv = tid >> 6, l = tid & 63;
    const int col = wv * 16 + (l & 15);
    const int g = l >> 4;
    f16x8 bfr[4];
    #pragma unroll
    for (int t = 0; t < 4; t++)
        #pragma unroll
        for (int e = 0; e < 8; e++)
            bfr[t][e] = Wh[(t * 32 + g * 8 + e) * 64 + col];

    f32x4 accs[4];
    #pragma unroll
    for (int nt = 0; nt < 4; nt++) {
        f32x4 acc = {0.f, 0.f, 0.f, 0.f};
        const int row = nt * 16 + (l & 15);
        #pragma unroll
        for (int t = 0; t < 4; t++) {
            const int off = (row * 256 + (t * 32 + g * 8) * 2) ^ ((row & 7) << 4);
            f16x8 af = *(const f16x8*)((const char*)xs + off);
            acc = __builtin_amdgcn_mfma_f32_16x16x32_f16(af, bfr[t], acc, 0, 0, 0);
        }
        accs[nt] = acc;
    }
    __syncthreads();                            // all waves done reading xs

    _Float16* htile = xs;                       // 64 x HTS (9.2KB, fits in xs region)
    #pragma unroll
    for (int nt = 0; nt < 4; nt++) {
        #pragma unroll
        for (int r = 0; r < 4; r++) {
            const int nl = nt * 16 + g * 4 + r;
            const float v = (float)accs[nt][r];
            htile[nl * HTS + col] = (_Float16)v;
            const int n = node0 + nl;
            if (n < nnodes) h1[(long)n * 64 + col] = __float2half(v);
        }
    }
    __syncthreads();

    // att1 logits from htile: thread -> (node, c); c: 0=el.h0 1=el.h1 2=er.h0 3=er.h1
    const int nodeL = tid >> 2, c4 = tid & 3, hh = c4 & 1;
    const float* av = ((c4 >> 1) ? ar1 : al1) + hh * 32;
    const _Float16* hrow = htile + nodeL * HTS + hh * 32;
    float sacc = 0.f;
    #pragma unroll
    for (int d = 0; d < 32; d++) sacc = fmaf((float)hrow[d], av[d], sacc);
    const int n = node0 + nodeL;
    if (n < nnodes) {
        if (c4 < 2) el[(long)n * 2 + hh] = sacc;
        else        er[(long)n * 2 + hh] = sacc;
    }
}

// ---- per-256-node-bin LDS bucket build -> CSR (ndesc + packed eadj) ----
__global__ __launch_bounds__(256)
void k_scatter(const unsigned* __restrict__ binbuf, int* __restrict__ gcur,
               int2* __restrict__ ndesc, int* __restrict__ eadj, int nnodes)
{
    extern __shared__ int lds[];          // ldeg[256] lscan[256] lbuck[CAP][256]
    int* ldeg  = lds;
    int* lscan = lds + 256;
    int* lbuck = lds + 512;
    __shared__ int sbase;
    const int t = threadIdx.x, b = blockIdx.x;
    const int nb0 = b << 8;
    ldeg[t] = 0;
    __syncthreads();
    const int cnt = min(max(gcur[b], 0), BCAP);
    const unsigned* recs = binbuf + (long)b * BCAP;
    for (int i = t; i < cnt; i += 256) {
        const unsigned r = recs[i];
        const int nl  = (int)(r & 255u);
        const int pos = atomicAdd(&ldeg[nl], 1);
        if (pos < CAP) lbuck[pos * 256 + nl] = (int)(r >> 8);
    }
    __syncthreads();
    const int dn = min(ldeg[t], CAP);
    lscan[t] = dn;
    __syncthreads();
    for (int o = 1; o < 256; o <<= 1) {           // inclusive scan
        const int v = lscan[t];
        const int u = (t >= o) ? lscan[t - o] : 0;
        __syncthreads();
        lscan[t] = v + u;
        __syncthreads();
    }
    if (t == 0) sbase = atomicAdd(&gcur[MAXB], lscan[255]);
    __syncthreads();
    const int start = sbase + lscan[t] - dn;
    const int n = nb0 + t;
    if (n < nnodes) ndesc[n] = make_int2(start, dn);
    for (int i = 0; i < dn; i++) eadj[start + i] = lbuck[i * 256 + t];
}

// ---- cooperative back half: agg1 -> gemm2(+att2) -> agg2 ----
__global__ __launch_bounds__(256, 8)
void k_back(const __half* __restrict__ h1, const float* __restrict__ el1,
            const float* __restrict__ er1, const int2* __restrict__ ndesc,
            const int* __restrict__ eadj, const float* __restrict__ b1,
            const float* __restrict__ W2, const float* __restrict__ al2,
            const float* __restrict__ ar2, const float* __restrict__ b2,
            __half* __restrict__ o1, __half* __restrict__ h2,
            float* __restrict__ el2, float* __restrict__ er2,
            float* __restrict__ out, int nnodes)
{
    __shared__ alignas(16) char smem[16 * 1024];
    cg::grid_group gg = cg::this_grid();
    const int w = threadIdx.x >> 6, lane = threadIdx.x & 63;

    // ================= phase 1: agg layer 1 -> o1 (fp16) =================
    {
        int*    sb = (int*)smem;                  // [4][64]
        float2* wb = (float2*)(smem + 1024);      // [4][64]
        const int NB4 = (nnodes + 3) >> 2;
        for (int vb = blockIdx.x; vb < NB4; vb += gridDim.x) {
            const int n = vb * 4 + w;
            if (n >= nnodes) continue;            // wave-uniform, no barriers inside
            const int2 nd = ndesc[n];
            const int dn = nd.y;
            const int sv = (lane < dn) ? eadj[nd.x + lane] : 0;
            sb[w * 64 + lane] = sv;

            const float2 ernv = ((const float2*)er1)[n];
            const float2 elv  = ((const float2*)el1)[sv];
            float e0 = elv.x + ernv.x; e0 = (e0 > 0.f) ? e0 : 0.2f * e0;
            float e1 = elv.y + ernv.y; e1 = (e1 > 0.f) ? e1 : 0.2f * e1;
            const float w0 = (lane < dn) ? __expf(e0) : 0.f;
            const float w1 = (lane < dn) ? __expf(e1) : 0.f;
            wb[w * 64 + lane] = make_float2(w0, w1);
            float s0 = w0, s1 = w1;
            #pragma unroll
            for (int off = 32; off; off >>= 1) {
                s0 += __shfl_xor(s0, off, 64);
                s1 += __shfl_xor(s1, off, 64);
            }
            const float inv0 = (s0 > 0.f) ? 1.f / s0 : 0.f;
            const float inv1 = (s1 > 0.f) ? 1.f / s1 : 0.f;

            const int q = lane >> 3, c8 = lane & 7, hh = c8 >> 2;
            const float invC = hh ? inv1 : inv0;
            float acc[8] = {0.f,0.f,0.f,0.f,0.f,0.f,0.f,0.f};
            for (int i = 0; i < dn; i += 16) {
                const int   sA = sb[w * 64 + i + q],  sB = sb[w * 64 + i + 8 + q];
                const float wA = ((const float*)&wb[w * 64 + i + q])[hh];
                const float wB = ((const float*)&wb[w * 64 + i + 8 + q])[hh];
                union { float4 f4; __half2 h2v[4]; } uA, uB;
                uA.f4 = *(const float4*)(h1 + (long)sA * 64 + c8 * 8);
                uB.f4 = *(const float4*)(h1 + (long)sB * 64 + c8 * 8);
                #pragma unroll
                for (int j = 0; j < 4; j++) {
                    const float2 xa = __half22float2(uA.h2v[j]);
                    const float2 xb = __half22float2(uB.h2v[j]);
                    acc[2*j]   = fmaf(xa.x, wA, acc[2*j]);
                    acc[2*j+1] = fmaf(xa.y, wA, acc[2*j+1]);
                    acc[2*j]   = fmaf(xb.x, wB, acc[2*j]);
                    acc[2*j+1] = fmaf(xb.y, wB, acc[2*j+1]);
                }
            }
            #pragma unroll
            for (int j = 0; j < 8; j++) {
                acc[j] += __shfl_xor(acc[j], 8, 64);
                acc[j] += __shfl_xor(acc[j], 16, 64);
                acc[j] += __shfl_xor(acc[j], 32, 64);
            }
            if (q == 0) {
                f16x8 ov;
                #pragma unroll
                for (int j = 0; j < 8; j++)
                    ov[j] = (_Float16)fmaxf(acc[j] * invC + b1[c8 * 8 + j], 0.f);
                *(f16x8*)((char*)o1 + (long)n * 128 + c8 * 16) = ov;
            }
        }
    }
    gg.sync();

    // ============ phase 2: gemm2 via MFMA (B2h in LDS) -> h2, el2, er2 ============
    {
        _Float16* B2s = (_Float16*)smem;             // [64][64]: W2 | col32=W2·al2 | col33=W2·ar2 | 0
        _Float16* xs  = (_Float16*)(smem + 8192);    // 64x64 swizzled
        for (int i = threadIdx.x; i < 64 * 64; i += 256) {
            const int k = i >> 6, c = i & 63;
            float s = 0.f;
            if (c < 32) s = W2[k * 32 + c];
            else if (c < 34) {
                const float* a = (c == 32) ? al2 : ar2;
                #pragma unroll
                for (int d = 0; d < 32; d++) s += W2[k * 32 + d] * a[d];
            }
            B2s[i] = (_Float16)s;
        }
        __syncthreads();

        const int wv = threadIdx.x >> 6, l = threadIdx.x & 63;
        const int col = wv * 16 + (l & 15);
        const int g2 = l >> 4;
        f16x8 bfr[2];
        if (wv < 3) {
            #pragma unroll
            for (int t = 0; t < 2; t++)
                #pragma unroll
                for (int e = 0; e < 8; e++)
                    bfr[t][e] = B2s[(t * 32 + g2 * 8 + e) * 64 + col];
        }
        const int NB64 = (nnodes + 63) >> 6;
        for (int vb = blockIdx.x; vb < NB64; vb += gridDim.x) {
            const int node0 = vb * 64;
            for (int cc = threadIdx.x; cc < 512; cc += 256) {
                const int row = cc >> 3, k8 = cc & 7;
                const int n = node0 + row;
                f16x8 hv = {0,0,0,0,0,0,0,0};
                if (n < nnodes) hv = *(const f16x8*)((const char*)o1 + (long)n * 128 + k8 * 16);
                const int off = (row * 128 + k8 * 16) ^ ((row & 7) << 4);
                *(f16x8*)((char*)xs + off) = hv;
            }
            __syncthreads();
            if (wv < 3) {
                #pragma unroll
                for (int nt = 0; nt < 4; nt++) {
                    f32x4 acc = {0.f, 0.f, 0.f, 0.f};
                    const int row = nt * 16 + (l & 15);
                    #pragma unroll
                    for (int t = 0; t < 2; t++) {
                        const int off = (row * 128 + (t * 32 + g2 * 8) * 2) ^ ((row & 7) << 4);
                        f16x8 af = *(const f16x8*)((const char*)xs + off);
                        acc = __builtin_amdgcn_mfma_f32_16x16x32_f16(af, bfr[t], acc, 0, 0, 0);
                    }
                    #pragma unroll
                    for (int r = 0; r < 4; r++) {
                        const int n = node0 + nt * 16 + g2 * 4 + r;
                        if (n < nnodes) {
                            if (wv < 2) h2[(long)n * 32 + col] = __float2half((float)acc[r]);
                            else {
                                const int cc4 = l & 15;
                                if (cc4 == 0)      el2[n] = (float)acc[r];
                                else if (cc4 == 1) er2[n] = (float)acc[r];
                            }
                        }
                    }
                }
            }
            __syncthreads();
        }
    }
    gg.sync();

    // ================= phase 3: agg layer 2 -> out (fp32) =================
    {
        int*   sb = (int*)smem;                   // [4][64]
        float* wb = (float*)(smem + 1024);        // [4][64]
        const int NB4 = (nnodes + 3) >> 2;
        for (int vb = blockIdx.x; vb < NB4; vb += gridDim.x) {
            const int n = vb * 4 + w;
            if (n >= nnodes) continue;
            const int2 nd = ndesc[n];
            const int dn = nd.y;
            const int sv = (lane < dn) ? eadj[nd.x + lane] : 0;
            sb[w * 64 + lane] = sv;

            const float ern = er2[n];
            float e = el2[sv] + ern; e = (e > 0.f) ? e : 0.2f * e;
            const float wt = (lane < dn) ? __expf(e) : 0.f;
            wb[w * 64 + lane] = wt;
            float s = wt;
            #pragma unroll
            for (int off = 32; off; off >>= 1) s += __shfl_xor(s, off, 64);
            const float inv = (s > 0.f) ? 1.f / s : 0.f;

            const int q = lane >> 2, c8 = lane & 3;
            float acc[8] = {0.f,0.f,0.f,0.f,0.f,0.f,0.f,0.f};
            for (int i = 0; i < dn; i += 16) {
                const int   sA = sb[w * 64 + i + q];
                const float wA = wb[w * 64 + i + q];
                union { float4 f4; __half2 h2v[4]; } uA;
                uA.f4 = *(const float4*)(h2 + (long)sA * 32 + c8 * 8);
                #pragma unroll
                for (int j = 0; j < 4; j++) {
                    const float2 xa = __half22float2(uA.h2v[j]);
                    acc[2*j]   = fmaf(xa.x, wA, acc[2*j]);
                    acc[2*j+1] = fmaf(xa.y, wA, acc[2*j+1]);
                }
            }
            #pragma unroll
            for (int j = 0; j < 8; j++) {
                acc[j] += __shfl_xor(acc[j], 4, 64);
                acc[j] += __shfl_xor(acc[j], 8, 64);
                acc[j] += __shfl_xor(acc[j], 16, 64);
                acc[j] += __shfl_xor(acc[j], 32, 64);
            }
            if (q == 0) {
                float r[8];
                #pragma unroll
                for (int j = 0; j < 8; j++)
                    r[j] = fmaxf(acc[j] * inv + b2[c8 * 8 + j], 0.f);
                float4* po = (float4*)(out + (long)n * 32 + c8 * 8);
                po[0] = make_float4(r[0], r[1], r[2], r[3]);
                po[1] = make_float4(r[4], r[5], r[6], r[7]);
            }
        }
    }
}

extern "C" void kernel_launch(void* const* d_in, const int* in_sizes, int n_in,
                              void* d_out, int out_size, void* d_ws, size_t ws_size,
                              hipStream_t stream)
{
    const float* feat = (const float*)d_in[0];
    const float* W1   = (const float*)d_in[1];
    const float* al1  = (const float*)d_in[2];
    const float* ar1  = (const float*)d_in[3];
    const float* b1   = (const float*)d_in[4];
    const float* W2   = (const float*)d_in[5];
    const float* al2  = (const float*)d_in[6];
    const float* ar2  = (const float*)d_in[7];
    const float* b2   = (const float*)d_in[8];
    const int*   src  = (const int*)d_in[9];
    const int*   dst  = (const int*)d_in[10];

    const int N  = in_sizes[0] / 128;   // 100000
    const int E  = in_sizes[9];         // 1.7M
    const int NB = (N + 255) >> 8;      // 391 bins

    char* ws = (char*)d_ws;
    size_t off = 0;
    auto alloc = [&](size_t bytes) -> void* {
        void* p = ws + off;
        off += (bytes + 255) & ~size_t(255);
        return p;
    };
    // region A: binbuf (front..scatter) aliased with o1 (back phase1..2)
    const size_t szA = ((size_t)NB * BCAP * 4 > (size_t)N * 64 * 2)
                     ? (size_t)NB * BCAP * 4 : (size_t)N * 64 * 2;
    char*     A      = (char*)    alloc(szA);
    unsigned* binbuf = (unsigned*)A;
    __half*   o1     = (__half*)  A;
    // region B: h1 (front..back phase1) aliased with h2 (back phase2..3)
    char*     Br     = (char*)    alloc((size_t)N * 64 * 2);
    __half*   h1     = (__half*)  Br;
    __half*   h2     = (__half*)  Br;
    int*      gcur   = (int*)     alloc((size_t)(MAXB + 1) * 4);
    int2*     ndesc  = (int2*)    alloc((size_t)N * 8);
    int*      eadj   = (int*)     alloc((size_t)E * 4);
    float*    el1    = (float*)   alloc((size_t)N * 2 * 4);
    float*    er1    = (float*)   alloc((size_t)N * 2 * 4);
    float*    el2    = (float*)   alloc((size_t)N * 4);
    float*    er2    = (float*)   alloc((size_t)N * 4);

    hipMemsetAsync(gcur, 0, (size_t)(MAXB + 1) * 4, stream);

    const int Gbin  = (E + TILE - 1) / TILE;     // 830
    const int Ggemm = (N + 63) / 64;             // 1563

    k_front<<<Gbin + Ggemm, 256, 0, stream>>>(src, dst, gcur, binbuf, E, Gbin,
                                              feat, W1, al1, ar1, h1, el1, er1, N);
    k_scatter<<<NB, 256, (512 + 256 * CAP) * 4, stream>>>(binbuf, gcur, ndesc, eadj, N);

    // cooperative back half: grid sized to guaranteed co-residency (256 CUs)
    int nbm = 0;
    hipOccupancyMaxActiveBlocksPerMultiprocessor(&nbm, (const void*)k_back, 256, 0);
    if (nbm < 1) nbm = 1;
    long grid = (long)nbm * 256;
    const long NB4 = ((long)N + 3) / 4;
    if (grid > NB4) grid = NB4;
    if (grid > 2048) grid = 2048;

    void* h1v = (void*)h1;  void* o1v = (void*)o1;  void* h2v = (void*)h2;
    int   Nv  = N;
    void* args[] = {&h1v, (void*)&el1, (void*)&er1, (void*)&ndesc, (void*)&eadj,
                    (void*)&b1, (void*)&W2, (void*)&al2, (void*)&ar2, (void*)&b2,
                    &o1v, &h2v, (void*)&el2, (void*)&er2, (void*)&d_out, &Nv};
    hipLaunchCooperativeKernel((const void*)k_back, dim3((unsigned)grid), dim3(256),
                               args, 0, stream);
}

// Round 11
// 293.726 us; speedup vs baseline: 2.0407x; 2.0407x over previous
//
#include <hip/hip_runtime.h>
#include <hip/hip_fp16.h>
#include <math.h>

// GAT 2-layer forward, MI355X.
// k_prew -> k_front[bin || mfma-gemm1+att1] -> k_scatter(CSR) -> k_agg1 -> k_gemm2 -> k_agg2
// Single-pass softmax (no max: logits O(5), shift-invariant), fp16 h tables,
// binned two-phase CSR adjacency build, MFMA for both GEMMs with fused logit columns.

constexpr int CAP  = 64;    // max in-degree (Poisson(16)+1, P(>=63)~4e-19)
constexpr int MAXB = 512;   // bin counter slots; gcur[MAXB] = global CSR edge cursor
constexpr int TILE = 2048;  // edges per bin block
constexpr int BCAP = 5120;  // records per 256-node bin (mean 4352, ~11 sigma)

typedef _Float16 f16x8 __attribute__((ext_vector_type(8)));
typedef float    f32x4 __attribute__((ext_vector_type(4)));

// ---- precompute: vh1[128][16] (att1 B-cols), B2h[64][64] (W2 | v2l | v2r | 0), zero gcur ----
__global__ __launch_bounds__(256)
void k_prew(const float* __restrict__ W1, const float* __restrict__ al1, const float* __restrict__ ar1,
            const float* __restrict__ W2, const float* __restrict__ al2, const float* __restrict__ ar2,
            _Float16* __restrict__ vh1, _Float16* __restrict__ B2h, int* __restrict__ gcur)
{
    const int t = threadIdx.x;
    for (int i = t; i < 128 * 16; i += 256) {       // cols: 0=el.h0 1=el.h1 2=er.h0 3=er.h1
        const int k = i >> 4, c = i & 15;
        float s = 0.f;
        if (c < 4) {
            const int h = c & 1;
            const float* a = (c >> 1) ? ar1 : al1;
            #pragma unroll
            for (int d = 0; d < 32; d++) s += W1[k * 64 + h * 32 + d] * a[h * 32 + d];
        }
        vh1[i] = (_Float16)s;
    }
    for (int i = t; i < 64 * 64; i += 256) {        // cols 0..31 = W2, 32 = W2·al2, 33 = W2·ar2
        const int k = i >> 6, c = i & 63;
        float s = 0.f;
        if (c < 32) s = W2[k * 32 + c];
        else if (c < 34) {
            const float* a = (c == 32) ? al2 : ar2;
            #pragma unroll
            for (int d = 0; d < 32; d++) s += W2[k * 32 + d] * a[d];
        }
        B2h[i] = (_Float16)s;
    }
    for (int b = t; b < MAXB + 1; b += 256) gcur[b] = 0;   // incl. CSR edge cursor
}

// ---- fused front: edge binning blocks + MFMA gemm1(+att1 logit cols) blocks ----
__global__ __launch_bounds__(256)
void k_front(const int* __restrict__ src, const int* __restrict__ dst,
             int* __restrict__ gcur, unsigned* __restrict__ binbuf, int E, int Gbin,
             const float* __restrict__ x, const float* __restrict__ W,
             const _Float16* __restrict__ vh1,
             __half* __restrict__ h1, float* __restrict__ el, float* __restrict__ er,
             int nnodes)
{
    __shared__ alignas(16) char smem[32 * 1024];
    const int tid = threadIdx.x;

    if ((int)blockIdx.x < Gbin) {
        // ---- bin role: 2048 edges -> packed records (src<<8 | dst&255) ----
        int* cnt  = (int*)smem;
        int* base = cnt + MAXB;
        for (int b = tid; b < MAXB; b += 256) cnt[b] = 0;
        __syncthreads();
        const int e0 = blockIdx.x * TILE;
        int lo[8]; unsigned rec[8]; int bn[8];
        #pragma unroll
        for (int u = 0; u < 8; u++) {
            const int e = e0 + u * 256 + tid;
            if (e < E) {
                const int d = dst[e];
                bn[u]  = d >> 8;
                rec[u] = ((unsigned)src[e] << 8) | (unsigned)(d & 255);
                lo[u]  = atomicAdd(&cnt[bn[u]], 1);
            } else bn[u] = -1;
        }
        __syncthreads();
        for (int b = tid; b < MAXB; b += 256) {
            const int c = cnt[b];
            base[b] = c ? atomicAdd(&gcur[b], c) : 0;
        }
        __syncthreads();
        #pragma unroll
        for (int u = 0; u < 8; u++) if (bn[u] >= 0) {
            const int p = base[bn[u]] + lo[u];
            if ((unsigned)p < (unsigned)BCAP)
                binbuf[(long)bn[u] * BCAP + p] = rec[u];
        }
        return;
    }

    // ---- gemm role: 64 nodes, x(fp32->fp16 swizzled LDS) @ W1 via MFMA 16x16x32 ----
    _Float16* xs = (_Float16*)smem;            // 64 x 128, XOR-swizzled
    _Float16* Wh = xs + 64 * 128;              // 128 x 64
    const int node0 = ((int)blockIdx.x - Gbin) * 64;

    for (int c = tid; c < 1024; c += 256) {
        const int row = c >> 4, k8 = c & 15;
        const int n = node0 + row;
        float4 v0 = make_float4(0, 0, 0, 0), v1 = v0;
        if (n < nnodes) {
            v0 = ((const float4*)x)[(long)n * 32 + k8 * 2];
            v1 = ((const float4*)x)[(long)n * 32 + k8 * 2 + 1];
        }
        f16x8 h;
        h[0] = v0.x; h[1] = v0.y; h[2] = v0.z; h[3] = v0.w;
        h[4] = v1.x; h[5] = v1.y; h[6] = v1.z; h[7] = v1.w;
        const int off = (row * 256 + k8 * 16) ^ ((row & 7) << 4);
        *(f16x8*)((char*)xs + off) = h;
    }
    for (int c = tid; c < 1024; c += 256) {
        const int k = c >> 3, j8 = (c & 7) * 8;
        float4 v0 = ((const float4*)W)[(k * 64 + j8) >> 2];
        float4 v1 = ((const float4*)W)[((k * 64 + j8) >> 2) + 1];
        f16x8 h;
        h[0] = v0.x; h[1] = v0.y; h[2] = v0.z; h[3] = v0.w;
        h[4] = v1.x; h[5] = v1.y; h[6] = v1.z; h[7] = v1.w;
        *(f16x8*)(Wh + k * 64 + j8) = h;
    }
    __syncthreads();

    const int wv = tid >> 6, l = tid & 63;
    const int col = wv * 16 + (l & 15);
    const int g = l >> 4;
    f16x8 bfr[4], vfr[4];
    #pragma unroll
    for (int t = 0; t < 4; t++)
        #pragma unroll
        for (int e = 0; e < 8; e++)
            bfr[t][e] = Wh[(t * 32 + g * 8 + e) * 64 + col];
    if (wv == 0) {
        #pragma unroll
        for (int t = 0; t < 4; t++)
            #pragma unroll
            for (int e = 0; e < 8; e++)
                vfr[t][e] = vh1[(t * 32 + g * 8 + e) * 16 + (l & 15)];
    }

    #pragma unroll
    for (int nt = 0; nt < 4; nt++) {
        f32x4 acc = {0.f, 0.f, 0.f, 0.f}, accv = {0.f, 0.f, 0.f, 0.f};
        const int row = nt * 16 + (l & 15);
        #pragma unroll
        for (int t = 0; t < 4; t++) {
            const int off = (row * 256 + (t * 32 + g * 8) * 2) ^ ((row & 7) << 4);
            f16x8 af = *(const f16x8*)((const char*)xs + off);
            acc = __builtin_amdgcn_mfma_f32_16x16x32_f16(af, bfr[t], acc, 0, 0, 0);
            if (wv == 0)
                accv = __builtin_amdgcn_mfma_f32_16x16x32_f16(af, vfr[t], accv, 0, 0, 0);
        }
        #pragma unroll
        for (int r = 0; r < 4; r++) {
            const int n = node0 + nt * 16 + g * 4 + r;
            if (n < nnodes) {
                h1[(long)n * 64 + col] = __float2half((float)acc[r]);
                if (wv == 0) {
                    const int c4 = l & 15;
                    if (c4 < 2)      el[n * 2 + c4]       = (float)accv[r];
                    else if (c4 < 4) er[n * 2 + (c4 - 2)] = (float)accv[r];
                }
            }
        }
    }
}

// ---- per-256-node-bin LDS bucket build -> CSR (ndesc + packed eadj) ----
__global__ __launch_bounds__(256)
void k_scatter(const unsigned* __restrict__ binbuf, int* __restrict__ gcur,
               int2* __restrict__ ndesc, int* __restrict__ eadj, int nnodes)
{
    extern __shared__ int lds[];          // ldeg[256] lscan[256] lbuck[CAP][256]
    int* ldeg  = lds;
    int* lscan = lds + 256;
    int* lbuck = lds + 512;
    __shared__ int sbase;
    const int t = threadIdx.x, b = blockIdx.x;
    const int nb0 = b << 8;
    ldeg[t] = 0;
    __syncthreads();
    const int cnt = min(max(gcur[b], 0), BCAP);
    const unsigned* recs = binbuf + (long)b * BCAP;
    for (int i = t; i < cnt; i += 256) {
        const unsigned r = recs[i];
        const int nl  = (int)(r & 255u);
        const int pos = atomicAdd(&ldeg[nl], 1);
        if (pos < CAP) lbuck[pos * 256 + nl] = (int)(r >> 8);
    }
    __syncthreads();
    const int dn = min(ldeg[t], CAP);
    lscan[t] = dn;
    __syncthreads();
    for (int o = 1; o < 256; o <<= 1) {           // inclusive scan
        const int v = lscan[t];
        const int u = (t >= o) ? lscan[t - o] : 0;
        __syncthreads();
        lscan[t] = v + u;
        __syncthreads();
    }
    if (t == 0) sbase = atomicAdd(&gcur[MAXB], lscan[255]);
    __syncthreads();
    const int start = sbase + lscan[t] - dn;
    const int n = nb0 + t;
    if (n < nnodes) ndesc[n] = make_int2(start, dn);
    for (int i = 0; i < dn; i++) eadj[start + i] = lbuck[i * 256 + t];
}

// ---- agg layer1: single-pass softmax + 16B-gather over CSR; o1 out fp16 ----
__global__ __launch_bounds__(256)
void k_agg1(const __half* __restrict__ hbuf, const float* __restrict__ el,
            const float* __restrict__ er, const int2* __restrict__ ndesc,
            const int* __restrict__ eadj, const float* __restrict__ b1,
            __half* __restrict__ o1, int nnodes)
{
    constexpr int OUT = 64;
    const int w = threadIdx.x >> 6, lane = threadIdx.x & 63;
    const int n = blockIdx.x * 4 + w;
    __shared__ int    sbuf[4][CAP];
    __shared__ float2 wbuf[4][CAP];
    if (n >= nnodes) return;                     // wave-uniform; no barriers below

    const int2 nd = ndesc[n];
    const int dn = nd.y;
    const int sv = (lane < dn) ? eadj[nd.x + lane] : 0;
    sbuf[w][lane] = sv;

    // weights for all <=64 edges in one parallel step (softmax shift-invariant, |e|<~6)
    const float2 ernv = ((const float2*)er)[n];
    const float2 elv  = ((const float2*)el)[sv];
    float e0 = elv.x + ernv.x; e0 = (e0 > 0.f) ? e0 : 0.2f * e0;
    float e1 = elv.y + ernv.y; e1 = (e1 > 0.f) ? e1 : 0.2f * e1;
    const float w0 = (lane < dn) ? __expf(e0) : 0.f;
    const float w1 = (lane < dn) ? __expf(e1) : 0.f;
    wbuf[w][lane] = make_float2(w0, w1);
    float s0 = w0, s1 = w1;
    #pragma unroll
    for (int off = 32; off; off >>= 1) {
        s0 += __shfl_xor(s0, off, 64);
        s1 += __shfl_xor(s1, off, 64);
    }
    const float inv0 = (s0 > 0.f) ? 1.f / s0 : 0.f;
    const float inv1 = (s1 > 0.f) ? 1.f / s1 : 0.f;

    // gather: 8 lanes/row (16B fp16 each), 16 edge slots/iter
    const int q = lane >> 3, c8 = lane & 7, hh = c8 >> 2;
    const float invC = hh ? inv1 : inv0;
    float acc[8] = {0.f,0.f,0.f,0.f,0.f,0.f,0.f,0.f};
    for (int i = 0; i < dn; i += 16) {
        const int   sA = sbuf[w][i + q],                     sB = sbuf[w][i + 8 + q];
        const float wA = ((const float*)&wbuf[w][i + q])[hh];
        const float wB = ((const float*)&wbuf[w][i + 8 + q])[hh];
        union { float4 f4; __half2 h2v[4]; } uA, uB;
        uA.f4 = *(const float4*)(hbuf + (long)sA * OUT + c8 * 8);
        uB.f4 = *(const float4*)(hbuf + (long)sB * OUT + c8 * 8);
        #pragma unroll
        for (int j = 0; j < 4; j++) {
            const float2 xa = __half22float2(uA.h2v[j]);
            const float2 xb = __half22float2(uB.h2v[j]);
            acc[2*j]   = fmaf(xa.x, wA, acc[2*j]);
            acc[2*j+1] = fmaf(xa.y, wA, acc[2*j+1]);
            acc[2*j]   = fmaf(xb.x, wB, acc[2*j]);
            acc[2*j+1] = fmaf(xb.y, wB, acc[2*j+1]);
        }
    }
    #pragma unroll
    for (int j = 0; j < 8; j++) {
        acc[j] += __shfl_xor(acc[j], 8, 64);
        acc[j] += __shfl_xor(acc[j], 16, 64);
        acc[j] += __shfl_xor(acc[j], 32, 64);
    }
    if (q == 0) {
        f16x8 ov;
        #pragma unroll
        for (int j = 0; j < 8; j++)
            ov[j] = (_Float16)fmaxf(acc[j] * invC + b1[c8 * 8 + j], 0.f);
        *(f16x8*)((char*)o1 + (long)n * 128 + c8 * 16) = ov;
    }
}

// ---- gemm2 via MFMA: h2 = o1 @ W2 (fp16), el2/er2 from B-cols 32/33 ----
__global__ __launch_bounds__(256)
void k_gemm2(const __half* __restrict__ o1, const _Float16* __restrict__ B2h,
             __half* __restrict__ h2, float* __restrict__ el2, float* __restrict__ er2,
             int nnodes)
{
    __shared__ _Float16 xs[64 * 64];     // 64 rows x 64 k, XOR-swizzled (128B rows)
    const int tid = threadIdx.x;
    const int node0 = blockIdx.x * 64;

    for (int c = tid; c < 512; c += 256) {
        const int row = c >> 3, k8 = c & 7;
        const int n = node0 + row;
        f16x8 h = {0,0,0,0,0,0,0,0};
        if (n < nnodes) h = *(const f16x8*)((const char*)o1 + (long)n * 128 + k8 * 16);
        const int off = (row * 128 + k8 * 16) ^ ((row & 7) << 4);
        *(f16x8*)((char*)xs + off) = h;
    }
    __syncthreads();

    const int wv = tid >> 6, l = tid & 63;
    if (wv == 3) return;                         // cols 48..63 are zero padding
    const int col = wv * 16 + (l & 15);
    const int g = l >> 4;
    f16x8 bfr[2];
    #pragma unroll
    for (int t = 0; t < 2; t++)
        #pragma unroll
        for (int e = 0; e < 8; e++)
            bfr[t][e] = B2h[(t * 32 + g * 8 + e) * 64 + col];

    #pragma unroll
    for (int nt = 0; nt < 4; nt++) {
        f32x4 acc = {0.f, 0.f, 0.f, 0.f};
        const int row = nt * 16 + (l & 15);
        #pragma unroll
        for (int t = 0; t < 2; t++) {
            const int off = (row * 128 + (t * 32 + g * 8) * 2) ^ ((row & 7) << 4);
            f16x8 af = *(const f16x8*)((const char*)xs + off);
            acc = __builtin_amdgcn_mfma_f32_16x16x32_f16(af, bfr[t], acc, 0, 0, 0);
        }
        #pragma unroll
        for (int r = 0; r < 4; r++) {
            const int n = node0 + nt * 16 + g * 4 + r;
            if (n < nnodes) {
                if (wv < 2) h2[(long)n * 32 + col] = __float2half((float)acc[r]);
                else {
                    const int c4 = l & 15;
                    if (c4 == 0)      el2[n] = (float)acc[r];
                    else if (c4 == 1) er2[n] = (float)acc[r];
                }
            }
        }
    }
}

// ---- agg layer2 over CSR (final output, fp32) ----
__global__ __launch_bounds__(256)
void k_agg2(const __half* __restrict__ h2, const float* __restrict__ el2,
            const float* __restrict__ er2, const int2* __restrict__ ndesc,
            const int* __restrict__ eadj, const float* __restrict__ b2,
            float* __restrict__ out, int nnodes)
{
    const int w = threadIdx.x >> 6, lane = threadIdx.x & 63;
    const int n = blockIdx.x * 4 + w;
    __shared__ int   sbuf[4][CAP];
    __shared__ float wbuf[4][CAP];
    if (n >= nnodes) return;

    const int2 nd = ndesc[n];
    const int dn = nd.y;
    const int sv = (lane < dn) ? eadj[nd.x + lane] : 0;
    sbuf[w][lane] = sv;

    const float ern = er2[n];
    float e = el2[sv] + ern; e = (e > 0.f) ? e : 0.2f * e;
    const float wt = (lane < dn) ? __expf(e) : 0.f;
    wbuf[w][lane] = wt;
    float s = wt;
    #pragma unroll
    for (int off = 32; off; off >>= 1) s += __shfl_xor(s, off, 64);
    const float inv = (s > 0.f) ? 1.f / s : 0.f;

    // gather: 4 lanes/row (16B fp16 each), 16 edge slots/iter
    const int q = lane >> 2, c8 = lane & 3;
    float acc[8] = {0.f,0.f,0.f,0.f,0.f,0.f,0.f,0.f};
    for (int i = 0; i < dn; i += 16) {
        const int   sA = sbuf[w][i + q];
        const float wA = wbuf[w][i + q];
        union { float4 f4; __half2 h2v[4]; } uA;
        uA.f4 = *(const float4*)(h2 + (long)sA * 32 + c8 * 8);
        #pragma unroll
        for (int j = 0; j < 4; j++) {
            const float2 xa = __half22float2(uA.h2v[j]);
            acc[2*j]   = fmaf(xa.x, wA, acc[2*j]);
            acc[2*j+1] = fmaf(xa.y, wA, acc[2*j+1]);
        }
    }
    #pragma unroll
    for (int j = 0; j < 8; j++) {
        acc[j] += __shfl_xor(acc[j], 4, 64);
        acc[j] += __shfl_xor(acc[j], 8, 64);
        acc[j] += __shfl_xor(acc[j], 16, 64);
        acc[j] += __shfl_xor(acc[j], 32, 64);
    }
    if (q == 0) {
        float r[8];
        #pragma unroll
        for (int j = 0; j < 8; j++)
            r[j] = fmaxf(acc[j] * inv + b2[c8 * 8 + j], 0.f);
        float4* po = (float4*)(out + (long)n * 32 + c8 * 8);
        po[0] = make_float4(r[0], r[1], r[2], r[3]);
        po[1] = make_float4(r[4], r[5], r[6], r[7]);
    }
}

extern "C" void kernel_launch(void* const* d_in, const int* in_sizes, int n_in,
                              void* d_out, int out_size, void* d_ws, size_t ws_size,
                              hipStream_t stream)
{
    const float* feat = (const float*)d_in[0];
    const float* W1   = (const float*)d_in[1];
    const float* al1  = (const float*)d_in[2];
    const float* ar1  = (const float*)d_in[3];
    const float* b1   = (const float*)d_in[4];
    const float* W2   = (const float*)d_in[5];
    const float* al2  = (const float*)d_in[6];
    const float* ar2  = (const float*)d_in[7];
    const float* b2   = (const float*)d_in[8];
    const int*   src  = (const int*)d_in[9];
    const int*   dst  = (const int*)d_in[10];

    const int N  = in_sizes[0] / 128;   // 100000
    const int E  = in_sizes[9];         // 1.7M
    const int NB = (N + 255) >> 8;      // 391 bins

    char* ws = (char*)d_ws;
    size_t off = 0;
    auto alloc = [&](size_t bytes) -> void* {
        void* p = ws + off;
        off += (bytes + 255) & ~size_t(255);
        return p;
    };
    // region A: binbuf (front..scatter) aliased with o1 (agg1..gemm2)
    const size_t szA = ((size_t)NB * BCAP * 4 > (size_t)N * 64 * 2)
                     ? (size_t)NB * BCAP * 4 : (size_t)N * 64 * 2;
    char*     A      = (char*)    alloc(szA);
    unsigned* binbuf = (unsigned*)A;
    __half*   o1     = (__half*)  A;
    // region B: h1 (front..agg1) aliased with h2 (gemm2..agg2)
    char*     Br     = (char*)    alloc((size_t)N * 64 * 2);
    __half*   h1     = (__half*)  Br;
    __half*   h2     = (__half*)  Br;
    int*      gcur   = (int*)     alloc((size_t)(MAXB + 1) * 4);
    int2*     ndesc  = (int2*)    alloc((size_t)N * 8);
    int*      eadj   = (int*)     alloc((size_t)E * 4);
    float*    el1    = (float*)   alloc((size_t)N * 2 * 4);
    float*    er1    = (float*)   alloc((size_t)N * 2 * 4);
    float*    el2    = (float*)   alloc((size_t)N * 4);
    float*    er2    = (float*)   alloc((size_t)N * 4);
    _Float16* vh1    = (_Float16*)alloc(128 * 16 * 2);
    _Float16* B2h    = (_Float16*)alloc(64 * 64 * 2);

    const int Gbin  = (E + TILE - 1) / TILE;     // 830
    const int Ggemm = (N + 63) / 64;             // 1563

    k_prew<<<1, 256, 0, stream>>>(W1, al1, ar1, W2, al2, ar2, vh1, B2h, gcur);
    k_front<<<Gbin + Ggemm, 256, 0, stream>>>(src, dst, gcur, binbuf, E, Gbin,
                                              feat, W1, vh1, h1, el1, er1, N);
    k_scatter<<<NB, 256, (512 + 256 * CAP) * 4, stream>>>(binbuf, gcur, ndesc, eadj, N);
    k_agg1<<<(N + 3) / 4, 256, 0, stream>>>(h1, el1, er1, ndesc, eadj, b1, o1, N);
    k_gemm2<<<(N + 63) / 64, 256, 0, stream>>>(o1, B2h, h2, el2, er2, N);
    k_agg2<<<(N + 3) / 4, 256, 0, stream>>>(h2, el2, er2, ndesc, eadj, b2,
                                            (float*)d_out, N);
}